// Round 1
// baseline (498.486 us; speedup 1.0000x reference)
//
#include <hip/hip_runtime.h>
#include <hip/hip_bf16.h>
#include <math.h>

#define N_TOK 2048
#define DIM   1024
#define FF    2048
#define NEXP  8
#define NSLOT (N_TOK * 2)

typedef __attribute__((ext_vector_type(8))) short short8;
typedef __attribute__((ext_vector_type(4))) float f32x4;

__device__ __forceinline__ unsigned short f2bf(float f) {
    unsigned int u = __float_as_uint(f);
    u += 0x7FFFu + ((u >> 16) & 1u);   // round-to-nearest-even
    return (unsigned short)(u >> 16);
}

// ---------------- router: logits, softmax-free top-2 weights, counts ----------
__global__ __launch_bounds__(256) void k_router(const float* __restrict__ x,
        const float* __restrict__ Wg, int* __restrict__ hdr,
        int* __restrict__ tok_e, float* __restrict__ tok_w) {
    int wave = threadIdx.x >> 6, lane = threadIdx.x & 63;
    int t = blockIdx.x * 4 + wave;
    float acc[NEXP];
#pragma unroll
    for (int e = 0; e < NEXP; ++e) acc[e] = 0.f;
    const float* xr = x + (size_t)t * DIM;
    for (int d = lane; d < DIM; d += 64) {
        float xv = xr[d];
        const float* wr = Wg + d * NEXP;
#pragma unroll
        for (int e = 0; e < NEXP; ++e) acc[e] += xv * wr[e];
    }
#pragma unroll
    for (int off = 32; off > 0; off >>= 1) {
#pragma unroll
        for (int e = 0; e < NEXP; ++e) acc[e] += __shfl_down(acc[e], off);
    }
    if (lane == 0) {
        int e0 = 0;
#pragma unroll
        for (int e = 1; e < NEXP; ++e) if (acc[e] > acc[e0]) e0 = e;
        int e1 = -1;
#pragma unroll
        for (int e = 0; e < NEXP; ++e) {
            if (e == e0) continue;
            if (e1 < 0 || acc[e] > acc[e1]) e1 = e;
        }
        // renormalized top-2 softmax weights: denominators cancel
        float w0 = 1.f / (1.f + expf(acc[e1] - acc[e0]));
        tok_e[2 * t] = e0; tok_e[2 * t + 1] = e1;
        tok_w[2 * t] = w0; tok_w[2 * t + 1] = 1.f - w0;
        atomicAdd(&hdr[e0], 1);
        atomicAdd(&hdr[e1], 1);
    }
}

// ---------------- scan: exclusive prefix sum of counts -> base, cursor --------
__global__ void k_scan(int* hdr) {
    if (threadIdx.x == 0 && blockIdx.x == 0) {
        int s = 0;
        for (int e = 0; e < NEXP; ++e) {
            hdr[16 + e] = s;   // base
            hdr[8 + e]  = s;   // cursor
            s += hdr[e];
        }
        hdr[24] = s;
    }
}

// ---------------- assign: compact slots + gather x rows to bf16 ---------------
__global__ __launch_bounds__(256) void k_assign(const float* __restrict__ x,
        int* __restrict__ hdr, const int* __restrict__ tok_e,
        const float* __restrict__ tok_w, int* __restrict__ tok_slot,
        float* __restrict__ slot_w, unsigned short* __restrict__ xg) {
    __shared__ int sh[2];
    int t = blockIdx.x;
    if (threadIdx.x == 0) {
        int e0 = tok_e[2 * t], e1 = tok_e[2 * t + 1];
        int p0 = atomicAdd(&hdr[8 + e0], 1);
        int p1 = atomicAdd(&hdr[8 + e1], 1);
        tok_slot[2 * t] = p0; tok_slot[2 * t + 1] = p1;
        slot_w[p0] = tok_w[2 * t];
        slot_w[p1] = tok_w[2 * t + 1];
        sh[0] = p0; sh[1] = p1;
    }
    __syncthreads();
    int s0 = sh[0], s1 = sh[1];
    const float4* xr = (const float4*)(x + (size_t)t * DIM);
    float4 v = xr[threadIdx.x];
    ushort4 b;
    b.x = f2bf(v.x); b.y = f2bf(v.y); b.z = f2bf(v.z); b.w = f2bf(v.w);
    ((ushort4*)(xg + (size_t)s0 * DIM))[threadIdx.x] = b;
    ((ushort4*)(xg + (size_t)s1 * DIM))[threadIdx.x] = b;
}

// ---------------- expert dual-GEMM: h & s, fused exact GELU -> inner (bf16) ---
// block tile: 128 rows x 64 F-cols, K-step 32, 4 waves (2x2), wave = 64x32 per matrix
__global__ __launch_bounds__(256) void k_expert_hs(
        const unsigned short* __restrict__ xg,
        const float* __restrict__ Win, const float* __restrict__ Wsc,
        const float* __restrict__ b_in, const float* __restrict__ b_sc,
        const int* __restrict__ hdr, unsigned short* __restrict__ inner) {
    int e = blockIdx.z;
    int cnt = hdr[e];
    int mtile = blockIdx.y;
    if (mtile * 128 >= cnt) return;
    int base = hdr[16 + e];
    int f0 = blockIdx.x * 64;

    __shared__ unsigned short As[128 * 40];
    __shared__ unsigned short Bh[64 * 40];
    __shared__ unsigned short Bs[64 * 40];

    int tid = threadIdx.x;
    int wave = tid >> 6, lane = tid & 63;
    int lr = lane & 15, lq = lane >> 4;
    int wm = (wave >> 1) * 64, wf = (wave & 1) * 32;

    f32x4 acch[4][2], accs[4][2];
#pragma unroll
    for (int mi = 0; mi < 4; ++mi)
#pragma unroll
        for (int fi = 0; fi < 2; ++fi) {
            acch[mi][fi] = (f32x4){0.f, 0.f, 0.f, 0.f};
            accs[mi][fi] = (f32x4){0.f, 0.f, 0.f, 0.f};
        }

    const unsigned short* Arow = xg + (size_t)(base + mtile * 128) * DIM;
    int ar = tid >> 1, ah = (tid & 1) * 16;
    int bf = tid & 63, bkq = tid >> 6;  // 0..3
    const float* WinE = Win + (size_t)e * DIM * FF;
    const float* WscE = Wsc + (size_t)e * DIM * FF;

    for (int k0 = 0; k0 < DIM; k0 += 32) {
        const uint4* asrc = (const uint4*)(Arow + (size_t)ar * DIM + k0 + ah);
        uint4 a0 = asrc[0], a1 = asrc[1];
        const float* ph = WinE + (size_t)(k0 + bkq * 8) * FF + f0 + bf;
        const float* ps = WscE + (size_t)(k0 + bkq * 8) * FF + f0 + bf;
        unsigned int hv[4], sv[4];
#pragma unroll
        for (int j = 0; j < 4; ++j) {
            hv[j] = (unsigned)f2bf(ph[(size_t)(2 * j) * FF]) |
                    ((unsigned)f2bf(ph[(size_t)(2 * j + 1) * FF]) << 16);
            sv[j] = (unsigned)f2bf(ps[(size_t)(2 * j) * FF]) |
                    ((unsigned)f2bf(ps[(size_t)(2 * j + 1) * FF]) << 16);
        }
        __syncthreads();
        *(uint4*)&As[ar * 40 + ah] = a0;
        *(uint4*)&As[ar * 40 + ah + 8] = a1;
        *(uint4*)&Bh[bf * 40 + bkq * 8] = make_uint4(hv[0], hv[1], hv[2], hv[3]);
        *(uint4*)&Bs[bf * 40 + bkq * 8] = make_uint4(sv[0], sv[1], sv[2], sv[3]);
        __syncthreads();

        short8 af[4], bhf[2], bsf[2];
#pragma unroll
        for (int mi = 0; mi < 4; ++mi)
            af[mi] = *(const short8*)&As[(wm + mi * 16 + lr) * 40 + lq * 8];
#pragma unroll
        for (int fi = 0; fi < 2; ++fi) {
            bhf[fi] = *(const short8*)&Bh[(wf + fi * 16 + lr) * 40 + lq * 8];
            bsf[fi] = *(const short8*)&Bs[(wf + fi * 16 + lr) * 40 + lq * 8];
        }
#pragma unroll
        for (int mi = 0; mi < 4; ++mi)
#pragma unroll
            for (int fi = 0; fi < 2; ++fi) {
                acch[mi][fi] = __builtin_amdgcn_mfma_f32_16x16x32_bf16(
                    af[mi], bhf[fi], acch[mi][fi], 0, 0, 0);
                accs[mi][fi] = __builtin_amdgcn_mfma_f32_16x16x32_bf16(
                    af[mi], bsf[fi], accs[mi][fi], 0, 0, 0);
            }
    }

#pragma unroll
    for (int fi = 0; fi < 2; ++fi) {
        int f = f0 + wf + fi * 16 + lr;
        float bi = b_in[e * FF + f];
        float bs2 = b_sc[e * FF + f];
#pragma unroll
        for (int mi = 0; mi < 4; ++mi) {
#pragma unroll
            for (int r = 0; r < 4; ++r) {
                int rl = wm + mi * 16 + lq * 4 + r;
                int grow = mtile * 128 + rl;
                if (grow < cnt) {
                    float h = acch[mi][fi][r] + bi;
                    float s = accs[mi][fi][r] + bs2;
                    float g = 0.5f * h * (1.f + erff(h * 0.70710678f));
                    inner[(size_t)(base + grow) * FF + f] = f2bf(g * s);
                }
            }
        }
    }
}

// ---------------- expert out-GEMM: inner @ W_out, scaled by slot weight ------
// block tile: 128 rows x 128 D-cols, K-step 32, 4 waves (2x2), wave = 64x64
__global__ __launch_bounds__(256) void k_expert_out(
        const unsigned short* __restrict__ inner,
        const float* __restrict__ Wout, const float* __restrict__ b_out,
        const int* __restrict__ hdr, const float* __restrict__ slot_w,
        float* __restrict__ ybuf) {
    int e = blockIdx.z;
    int cnt = hdr[e];
    int mtile = blockIdx.y;
    if (mtile * 128 >= cnt) return;
    int base = hdr[16 + e];
    int d0 = blockIdx.x * 128;

    __shared__ unsigned short As[128 * 40];
    __shared__ unsigned short Bt[128 * 40];

    int tid = threadIdx.x;
    int wave = tid >> 6, lane = tid & 63;
    int lr = lane & 15, lq = lane >> 4;
    int wm = (wave >> 1) * 64, wn = (wave & 1) * 64;

    f32x4 acc[4][4];
#pragma unroll
    for (int mi = 0; mi < 4; ++mi)
#pragma unroll
        for (int ni = 0; ni < 4; ++ni) acc[mi][ni] = (f32x4){0.f, 0.f, 0.f, 0.f};

    const unsigned short* Arow = inner + (size_t)(base + mtile * 128) * FF;
    int ar = tid >> 1, ah = (tid & 1) * 16;
    int bd = tid & 127, bkq = tid >> 7;  // 0..1
    const float* W = Wout + (size_t)e * FF * DIM;

    for (int k0 = 0; k0 < FF; k0 += 32) {
        const uint4* asrc = (const uint4*)(Arow + (size_t)ar * FF + k0 + ah);
        uint4 a0 = asrc[0], a1 = asrc[1];
        const float* pw = W + (size_t)(k0 + bkq * 16) * DIM + d0 + bd;
        unsigned int wv[8];
#pragma unroll
        for (int j = 0; j < 8; ++j) {
            wv[j] = (unsigned)f2bf(pw[(size_t)(2 * j) * DIM]) |
                    ((unsigned)f2bf(pw[(size_t)(2 * j + 1) * DIM]) << 16);
        }
        __syncthreads();
        *(uint4*)&As[ar * 40 + ah] = a0;
        *(uint4*)&As[ar * 40 + ah + 8] = a1;
        *(uint4*)&Bt[bd * 40 + bkq * 16] = make_uint4(wv[0], wv[1], wv[2], wv[3]);
        *(uint4*)&Bt[bd * 40 + bkq * 16 + 8] = make_uint4(wv[4], wv[5], wv[6], wv[7]);
        __syncthreads();

        short8 af[4], bfm[4];
#pragma unroll
        for (int mi = 0; mi < 4; ++mi)
            af[mi] = *(const short8*)&As[(wm + mi * 16 + lr) * 40 + lq * 8];
#pragma unroll
        for (int ni = 0; ni < 4; ++ni)
            bfm[ni] = *(const short8*)&Bt[(wn + ni * 16 + lr) * 40 + lq * 8];
#pragma unroll
        for (int mi = 0; mi < 4; ++mi)
#pragma unroll
            for (int ni = 0; ni < 4; ++ni)
                acc[mi][ni] = __builtin_amdgcn_mfma_f32_16x16x32_bf16(
                    af[mi], bfm[ni], acc[mi][ni], 0, 0, 0);
    }

#pragma unroll
    for (int ni = 0; ni < 4; ++ni) {
        int d = d0 + wn + ni * 16 + lr;
        float bo = b_out[e * DIM + d];
#pragma unroll
        for (int mi = 0; mi < 4; ++mi) {
#pragma unroll
            for (int r = 0; r < 4; ++r) {
                int rl = wm + mi * 16 + lq * 4 + r;
                int grow = mtile * 128 + rl;
                if (grow < cnt) {
                    int slot = base + grow;
                    ybuf[(size_t)slot * DIM + d] = (acc[mi][ni][r] + bo) * slot_w[slot];
                }
            }
        }
    }
}

// ---------------- combine: out[t] = ybuf[slot0] + ybuf[slot1] ----------------
__global__ __launch_bounds__(256) void k_combine(const float* __restrict__ ybuf,
        const int* __restrict__ tok_slot, float* __restrict__ out) {
    int t = blockIdx.x;
    int s0 = tok_slot[2 * t], s1 = tok_slot[2 * t + 1];
    const float4* y0 = (const float4*)(ybuf + (size_t)s0 * DIM);
    const float4* y1 = (const float4*)(ybuf + (size_t)s1 * DIM);
    float4 a = y0[threadIdx.x], b = y1[threadIdx.x];
    float4 r;
    r.x = a.x + b.x; r.y = a.y + b.y; r.z = a.z + b.z; r.w = a.w + b.w;
    ((float4*)(out + (size_t)t * DIM))[threadIdx.x] = r;
}

extern "C" void kernel_launch(void* const* d_in, const int* in_sizes, int n_in,
                              void* d_out, int out_size, void* d_ws, size_t ws_size,
                              hipStream_t stream) {
    (void)in_sizes; (void)n_in; (void)out_size; (void)ws_size;
    const float* x    = (const float*)d_in[0];
    const float* Wg   = (const float*)d_in[1];
    const float* Win  = (const float*)d_in[2];
    const float* b_in = (const float*)d_in[3];
    const float* Wsc  = (const float*)d_in[4];
    const float* b_sc = (const float*)d_in[5];
    const float* Wout = (const float*)d_in[6];
    const float* b_out= (const float*)d_in[7];
    float* out = (float*)d_out;

    char* ws = (char*)d_ws;
    int*   hdr      = (int*)ws;                       // 64 ints: counts/cursor/base
    int*   tok_e    = (int*)(ws + 256);               // 2*N ints
    float* tok_w    = (float*)(ws + 16640);           // 2*N floats
    int*   tok_slot = (int*)(ws + 33024);             // 2*N ints
    float* slot_w   = (float*)(ws + 49408);           // NSLOT floats
    unsigned short* xg    = (unsigned short*)(ws + 65792);              // NSLOT x DIM bf16 (8 MB)
    unsigned short* inner = (unsigned short*)(ws + 65792 + 8388608);    // NSLOT x FF bf16 (16 MB)
    float* ybuf = (float*)(ws + 65792 + 8388608 + 16777216);            // NSLOT x DIM f32 (16 MB)

    hipMemsetAsync(hdr, 0, 256, stream);
    k_router<<<dim3(N_TOK / 4), dim3(256), 0, stream>>>(x, Wg, hdr, tok_e, tok_w);
    k_scan<<<dim3(1), dim3(64), 0, stream>>>(hdr);
    k_assign<<<dim3(N_TOK), dim3(256), 0, stream>>>(x, hdr, tok_e, tok_w, tok_slot, slot_w, xg);
    k_expert_hs<<<dim3(FF / 64, 16, NEXP), dim3(256), 0, stream>>>(xg, Win, Wsc, b_in, b_sc, hdr, inner);
    k_expert_out<<<dim3(DIM / 128, 16, NEXP), dim3(256), 0, stream>>>(inner, Wout, b_out, hdr, slot_w, ybuf);
    k_combine<<<dim3(N_TOK), dim3(256), 0, stream>>>(ybuf, tok_slot, out);
}

// Round 2
// 471.972 us; speedup vs baseline: 1.0562x; 1.0562x over previous
//
#include <hip/hip_runtime.h>
#include <hip/hip_bf16.h>
#include <math.h>

#define N_TOK 2048
#define DIM   1024
#define FF    2048
#define NEXP  8
#define NSLOT (N_TOK * 2)

typedef __attribute__((ext_vector_type(8))) short short8;
typedef __attribute__((ext_vector_type(4))) float f32x4;
typedef _Float16 half_t;
typedef __attribute__((ext_vector_type(4))) _Float16 h16x4;

__device__ __forceinline__ unsigned short f2bf(float f) {
    unsigned int u = __float_as_uint(f);
    u += 0x7FFFu + ((u >> 16) & 1u);   // round-to-nearest-even
    return (unsigned short)(u >> 16);
}

// async global->LDS 16B: LDS dst is wave-uniform base + lane*16
#define GLOAD_LDS16(g, l) \
    __builtin_amdgcn_global_load_lds((const __attribute__((address_space(1))) unsigned int*)(g), \
                                     (__attribute__((address_space(3))) unsigned int*)(l), 16, 0, 0)

// ---------------- router ------------------------------------------------------
__global__ __launch_bounds__(256) void k_router(const float* __restrict__ x,
        const float* __restrict__ Wg, int* __restrict__ hdr,
        int* __restrict__ tok_e, float* __restrict__ tok_w) {
    int wave = threadIdx.x >> 6, lane = threadIdx.x & 63;
    int t = blockIdx.x * 4 + wave;
    float acc[NEXP];
#pragma unroll
    for (int e = 0; e < NEXP; ++e) acc[e] = 0.f;
    const float* xr = x + (size_t)t * DIM;
    for (int d = lane; d < DIM; d += 64) {
        float xv = xr[d];
        const float* wr = Wg + d * NEXP;
#pragma unroll
        for (int e = 0; e < NEXP; ++e) acc[e] += xv * wr[e];
    }
#pragma unroll
    for (int off = 32; off > 0; off >>= 1) {
#pragma unroll
        for (int e = 0; e < NEXP; ++e) acc[e] += __shfl_down(acc[e], off);
    }
    if (lane == 0) {
        int e0 = 0;
#pragma unroll
        for (int e = 1; e < NEXP; ++e) if (acc[e] > acc[e0]) e0 = e;
        int e1 = -1;
#pragma unroll
        for (int e = 0; e < NEXP; ++e) {
            if (e == e0) continue;
            if (e1 < 0 || acc[e] > acc[e1]) e1 = e;
        }
        float w0 = 1.f / (1.f + expf(acc[e1] - acc[e0]));
        tok_e[2 * t] = e0; tok_e[2 * t + 1] = e1;
        tok_w[2 * t] = w0; tok_w[2 * t + 1] = 1.f - w0;
        atomicAdd(&hdr[e0], 1);
        atomicAdd(&hdr[e1], 1);
    }
}

// ---------------- scan --------------------------------------------------------
__global__ void k_scan(int* hdr) {
    if (threadIdx.x == 0 && blockIdx.x == 0) {
        int s = 0;
        for (int e = 0; e < NEXP; ++e) {
            hdr[16 + e] = s;
            hdr[8 + e]  = s;
            s += hdr[e];
        }
        hdr[24] = s;
    }
}

// ---------------- assign: slots + gather x -> bf16 ----------------------------
__global__ __launch_bounds__(256) void k_assign(const float* __restrict__ x,
        int* __restrict__ hdr, const int* __restrict__ tok_e,
        int* __restrict__ tok_slot, unsigned short* __restrict__ xg) {
    __shared__ int sh[2];
    int t = blockIdx.x;
    if (threadIdx.x == 0) {
        int e0 = tok_e[2 * t], e1 = tok_e[2 * t + 1];
        int p0 = atomicAdd(&hdr[8 + e0], 1);
        int p1 = atomicAdd(&hdr[8 + e1], 1);
        tok_slot[2 * t] = p0; tok_slot[2 * t + 1] = p1;
        sh[0] = p0; sh[1] = p1;
    }
    __syncthreads();
    int s0 = sh[0], s1 = sh[1];
    const float4* xr = (const float4*)(x + (size_t)t * DIM);
    float4 v = xr[threadIdx.x];
    ushort4 b;
    b.x = f2bf(v.x); b.y = f2bf(v.y); b.z = f2bf(v.z); b.w = f2bf(v.w);
    ((ushort4*)(xg + (size_t)s0 * DIM))[threadIdx.x] = b;
    ((ushort4*)(xg + (size_t)s1 * DIM))[threadIdx.x] = b;
}

// ---------------- expert dual-GEMM h & s + exact GELU -> inner (bf16) --------
// tile 128 x 64F, K-step 32, 4 waves 2x2 (wave = 64x32). A via global_load_lds,
// B in [kq][f][8] 16B-chunk layout (conflict-free), W prefetch pipelined.
__global__ __launch_bounds__(256, 4) void k_expert_hs(
        const unsigned short* __restrict__ xg,
        const float* __restrict__ Win, const float* __restrict__ Wsc,
        const float* __restrict__ b_in, const float* __restrict__ b_sc,
        const int* __restrict__ hdr, unsigned short* __restrict__ inner) {
    int e = blockIdx.z;
    int cnt = hdr[e];
    int mtile = blockIdx.y;
    if (mtile * 128 >= cnt) return;
    int base = hdr[16 + e];
    int f0 = blockIdx.x * 64;

    __shared__ unsigned short As[128 * 32];   // [row][k], 64B rows
    __shared__ unsigned short Bh[4 * 64 * 8]; // [kq][f][8]
    __shared__ unsigned short Bs[4 * 64 * 8];

    int tid = threadIdx.x;
    int wave = tid >> 6, lane = tid & 63;
    int lr = lane & 15, lq = lane >> 4;
    int wm = (wave >> 1) * 64, wf = (wave & 1) * 32;

    f32x4 acch[4][2], accs[4][2];
#pragma unroll
    for (int mi = 0; mi < 4; ++mi)
#pragma unroll
        for (int fi = 0; fi < 2; ++fi) {
            acch[mi][fi] = (f32x4){0.f, 0.f, 0.f, 0.f};
            accs[mi][fi] = (f32x4){0.f, 0.f, 0.f, 0.f};
        }

    const unsigned short* Arow = xg + (size_t)(base + mtile * 128) * DIM;
    int arow = wave * 16 + (lane >> 2);
    int akk  = (lane & 3) * 8;

    int bf = tid & 63, bkq = tid >> 6;
    const float* ph_base = Win + (size_t)e * DIM * FF + f0 + bf;
    const float* ps_base = Wsc + (size_t)e * DIM * FF + f0 + bf;

    unsigned hv[4], sv[4];
    {
        const float* ph = ph_base + (size_t)(bkq * 8) * FF;
        const float* ps = ps_base + (size_t)(bkq * 8) * FF;
#pragma unroll
        for (int j = 0; j < 4; ++j) {
            hv[j] = (unsigned)f2bf(ph[(size_t)(2 * j) * FF]) |
                    ((unsigned)f2bf(ph[(size_t)(2 * j + 1) * FF]) << 16);
            sv[j] = (unsigned)f2bf(ps[(size_t)(2 * j) * FF]) |
                    ((unsigned)f2bf(ps[(size_t)(2 * j + 1) * FF]) << 16);
        }
    }

    for (int k0 = 0; k0 < DIM; k0 += 32) {
        __syncthreads();   // prior frag reads done
        // A: 128 rows x 32 k via DMA, 2 issues/wave
        const unsigned short* gA = Arow + (size_t)arow * DIM + k0 + akk;
        GLOAD_LDS16(gA, &As[(wave * 16) * 32]);
        GLOAD_LDS16(gA + (size_t)64 * DIM, &As[(64 + wave * 16) * 32]);
        // B: write prefetched regs
        *(uint4*)&Bh[(bkq * 64 + bf) * 8] = make_uint4(hv[0], hv[1], hv[2], hv[3]);
        *(uint4*)&Bs[(bkq * 64 + bf) * 8] = make_uint4(sv[0], sv[1], sv[2], sv[3]);
        __syncthreads();   // waits DMA + LDS writes

        unsigned hvN[4], svN[4];
        bool more = (k0 + 32 < DIM);
        if (more) {
            const float* ph = ph_base + (size_t)(k0 + 32 + bkq * 8) * FF;
            const float* ps = ps_base + (size_t)(k0 + 32 + bkq * 8) * FF;
#pragma unroll
            for (int j = 0; j < 4; ++j) {
                hvN[j] = (unsigned)f2bf(ph[(size_t)(2 * j) * FF]) |
                         ((unsigned)f2bf(ph[(size_t)(2 * j + 1) * FF]) << 16);
                svN[j] = (unsigned)f2bf(ps[(size_t)(2 * j) * FF]) |
                         ((unsigned)f2bf(ps[(size_t)(2 * j + 1) * FF]) << 16);
            }
        }

        short8 af[4], bhf[2], bsf[2];
#pragma unroll
        for (int mi = 0; mi < 4; ++mi)
            af[mi] = *(const short8*)&As[(wm + mi * 16 + lr) * 32 + lq * 8];
#pragma unroll
        for (int fi = 0; fi < 2; ++fi) {
            bhf[fi] = *(const short8*)&Bh[(lq * 64 + wf + fi * 16 + lr) * 8];
            bsf[fi] = *(const short8*)&Bs[(lq * 64 + wf + fi * 16 + lr) * 8];
        }
#pragma unroll
        for (int mi = 0; mi < 4; ++mi)
#pragma unroll
            for (int fi = 0; fi < 2; ++fi) {
                acch[mi][fi] = __builtin_amdgcn_mfma_f32_16x16x32_bf16(
                    af[mi], bhf[fi], acch[mi][fi], 0, 0, 0);
                accs[mi][fi] = __builtin_amdgcn_mfma_f32_16x16x32_bf16(
                    af[mi], bsf[fi], accs[mi][fi], 0, 0, 0);
            }
        if (more) {
#pragma unroll
            for (int j = 0; j < 4; ++j) { hv[j] = hvN[j]; sv[j] = svN[j]; }
        }
    }

#pragma unroll
    for (int fi = 0; fi < 2; ++fi) {
        int f = f0 + wf + fi * 16 + lr;
        float bi = b_in[e * FF + f];
        float bs2 = b_sc[e * FF + f];
#pragma unroll
        for (int mi = 0; mi < 4; ++mi) {
#pragma unroll
            for (int r = 0; r < 4; ++r) {
                int rl = wm + mi * 16 + lq * 4 + r;
                int grow = mtile * 128 + rl;
                if (grow < cnt) {
                    float h = acch[mi][fi][r] + bi;
                    float s = accs[mi][fi][r] + bs2;
                    float g = 0.5f * h * (1.f + erff(h * 0.70710678f));
                    inner[(size_t)(base + grow) * FF + f] = f2bf(g * s);
                }
            }
        }
    }
}

// ---------------- expert out-GEMM, split-K=2, fp16 partials -------------------
// tile 128 x 128D, K-range 1024 per block, 4 waves 2x2 (wave = 64x64)
__global__ __launch_bounds__(256, 4) void k_expert_out(
        const unsigned short* __restrict__ inner,
        const float* __restrict__ Wout,
        const int* __restrict__ hdr, half_t* __restrict__ pbuf) {
    int e = blockIdx.z & 7;
    int ks = blockIdx.z >> 3;
    int cnt = hdr[e];
    int mtile = blockIdx.y;
    if (mtile * 128 >= cnt) return;
    int base = hdr[16 + e];
    int d0 = blockIdx.x * 128;

    __shared__ unsigned short As[128 * 32];    // [row][k]
    __shared__ unsigned short Bt[4 * 128 * 8]; // [kq][d][8]

    int tid = threadIdx.x;
    int wave = tid >> 6, lane = tid & 63;
    int lr = lane & 15, lq = lane >> 4;
    int wm = (wave >> 1) * 64, wn = (wave & 1) * 64;

    f32x4 acc[4][4];
#pragma unroll
    for (int mi = 0; mi < 4; ++mi)
#pragma unroll
        for (int ni = 0; ni < 4; ++ni) acc[mi][ni] = (f32x4){0.f, 0.f, 0.f, 0.f};

    const unsigned short* Arow = inner + (size_t)(base + mtile * 128) * FF;
    int arow = wave * 16 + (lane >> 2);
    int akk  = (lane & 3) * 8;

    int bd = tid & 127, bq = tid >> 7;  // bq in 0..1; stages kq = 2bq, 2bq+1
    const float* Wb = Wout + (size_t)e * FF * DIM + d0 + bd;

    int kbeg = ks * (FF / 2), kend = kbeg + FF / 2;

    unsigned wv[8];
    {
        const float* pw = Wb + (size_t)(kbeg + bq * 16) * DIM;
#pragma unroll
        for (int j = 0; j < 8; ++j)
            wv[j] = (unsigned)f2bf(pw[(size_t)(2 * j) * DIM]) |
                    ((unsigned)f2bf(pw[(size_t)(2 * j + 1) * DIM]) << 16);
    }

    for (int k0 = kbeg; k0 < kend; k0 += 32) {
        __syncthreads();
        const unsigned short* gA = Arow + (size_t)arow * FF + k0 + akk;
        GLOAD_LDS16(gA, &As[(wave * 16) * 32]);
        GLOAD_LDS16(gA + (size_t)64 * FF, &As[(64 + wave * 16) * 32]);
        *(uint4*)&Bt[((2 * bq) * 128 + bd) * 8]     = make_uint4(wv[0], wv[1], wv[2], wv[3]);
        *(uint4*)&Bt[((2 * bq + 1) * 128 + bd) * 8] = make_uint4(wv[4], wv[5], wv[6], wv[7]);
        __syncthreads();

        unsigned wvN[8];
        bool more = (k0 + 32 < kend);
        if (more) {
            const float* pw = Wb + (size_t)(k0 + 32 + bq * 16) * DIM;
#pragma unroll
            for (int j = 0; j < 8; ++j)
                wvN[j] = (unsigned)f2bf(pw[(size_t)(2 * j) * DIM]) |
                         ((unsigned)f2bf(pw[(size_t)(2 * j + 1) * DIM]) << 16);
        }

        short8 af[4], bfm[4];
#pragma unroll
        for (int mi = 0; mi < 4; ++mi)
            af[mi] = *(const short8*)&As[(wm + mi * 16 + lr) * 32 + lq * 8];
#pragma unroll
        for (int ni = 0; ni < 4; ++ni)
            bfm[ni] = *(const short8*)&Bt[(lq * 128 + wn + ni * 16 + lr) * 8];
#pragma unroll
        for (int mi = 0; mi < 4; ++mi)
#pragma unroll
            for (int ni = 0; ni < 4; ++ni)
                acc[mi][ni] = __builtin_amdgcn_mfma_f32_16x16x32_bf16(
                    af[mi], bfm[ni], acc[mi][ni], 0, 0, 0);
        if (more) {
#pragma unroll
            for (int j = 0; j < 8; ++j) wv[j] = wvN[j];
        }
    }

    half_t* P = pbuf + (size_t)ks * NSLOT * DIM;
#pragma unroll
    for (int ni = 0; ni < 4; ++ni) {
        int d = d0 + wn + ni * 16 + lr;
#pragma unroll
        for (int mi = 0; mi < 4; ++mi) {
#pragma unroll
            for (int r = 0; r < 4; ++r) {
                int rl = wm + mi * 16 + lq * 4 + r;
                int grow = mtile * 128 + rl;
                if (grow < cnt)
                    P[(size_t)(base + grow) * DIM + d] = (half_t)acc[mi][ni][r];
            }
        }
    }
}

// ---------------- combine: out = w0*(p0+p1+b[e0]) + w1*(...) ------------------
__global__ __launch_bounds__(256) void k_combine(const half_t* __restrict__ pbuf,
        const int* __restrict__ tok_slot, const int* __restrict__ tok_e,
        const float* __restrict__ tok_w, const float* __restrict__ b_out,
        float* __restrict__ out) {
    int t = blockIdx.x;
    int d = threadIdx.x * 4;
    int s0 = tok_slot[2 * t], s1 = tok_slot[2 * t + 1];
    int e0 = tok_e[2 * t], e1 = tok_e[2 * t + 1];
    float w0 = tok_w[2 * t], w1 = tok_w[2 * t + 1];
    const half_t* pA = pbuf;
    const half_t* pB = pbuf + (size_t)NSLOT * DIM;
    h16x4 a0 = *(const h16x4*)&pA[(size_t)s0 * DIM + d];
    h16x4 a1 = *(const h16x4*)&pB[(size_t)s0 * DIM + d];
    h16x4 c0 = *(const h16x4*)&pA[(size_t)s1 * DIM + d];
    h16x4 c1 = *(const h16x4*)&pB[(size_t)s1 * DIM + d];
    float4 b0 = *(const float4*)&b_out[e0 * DIM + d];
    float4 b1 = *(const float4*)&b_out[e1 * DIM + d];
    float4 r;
    r.x = w0 * ((float)a0.x + (float)a1.x + b0.x) + w1 * ((float)c0.x + (float)c1.x + b1.x);
    r.y = w0 * ((float)a0.y + (float)a1.y + b0.y) + w1 * ((float)c0.y + (float)c1.y + b1.y);
    r.z = w0 * ((float)a0.z + (float)a1.z + b0.z) + w1 * ((float)c0.z + (float)c1.z + b1.z);
    r.w = w0 * ((float)a0.w + (float)a1.w + b0.w) + w1 * ((float)c0.w + (float)c1.w + b1.w);
    *(float4*)&out[(size_t)t * DIM + d] = r;
}

extern "C" void kernel_launch(void* const* d_in, const int* in_sizes, int n_in,
                              void* d_out, int out_size, void* d_ws, size_t ws_size,
                              hipStream_t stream) {
    (void)in_sizes; (void)n_in; (void)out_size; (void)ws_size;
    const float* x    = (const float*)d_in[0];
    const float* Wg   = (const float*)d_in[1];
    const float* Win  = (const float*)d_in[2];
    const float* b_in = (const float*)d_in[3];
    const float* Wsc  = (const float*)d_in[4];
    const float* b_sc = (const float*)d_in[5];
    const float* Wout = (const float*)d_in[6];
    const float* b_out= (const float*)d_in[7];
    float* out = (float*)d_out;

    char* ws = (char*)d_ws;
    int*   hdr      = (int*)ws;                 // counts / cursor / base
    int*   tok_e    = (int*)(ws + 256);
    float* tok_w    = (float*)(ws + 16640);
    int*   tok_slot = (int*)(ws + 33024);
    unsigned short* xg    = (unsigned short*)(ws + 65792);            // 8 MB
    unsigned short* inner = (unsigned short*)(ws + 65792 + 8388608);  // 16 MB
    half_t* pbuf = (half_t*)(ws + 65792 + 8388608 + 16777216);        // 2 x 8 MB fp16

    hipMemsetAsync(hdr, 0, 256, stream);
    k_router<<<dim3(N_TOK / 4), dim3(256), 0, stream>>>(x, Wg, hdr, tok_e, tok_w);
    k_scan<<<dim3(1), dim3(64), 0, stream>>>(hdr);
    k_assign<<<dim3(N_TOK), dim3(256), 0, stream>>>(x, hdr, tok_e, tok_slot, xg);
    k_expert_hs<<<dim3(FF / 64, 16, NEXP), dim3(256), 0, stream>>>(xg, Win, Wsc, b_in, b_sc, hdr, inner);
    k_expert_out<<<dim3(DIM / 128, 16, NEXP * 2), dim3(256), 0, stream>>>(inner, Wout, hdr, pbuf);
    k_combine<<<dim3(N_TOK), dim3(256), 0, stream>>>(pbuf, tok_slot, tok_e, tok_w, b_out, out);
}